// Round 1
// baseline (1113.746 us; speedup 1.0000x reference)
//
#include <hip/hip_runtime.h>
#include <hip/hip_fp16.h>
#include <cstdint>
#include <cstddef>

#define N_NODES_C  100000
#define N_EDGES_C  1600000
#define N_GRAPHS_C 256
#define HID_C      128
// 1/sqrt(1+1e-5)
#define BN_SCALE_C 0.9999950000374997f

#define SCAN_B 1024
#define SCAN_NB ((N_NODES_C + SCAN_B - 1) / SCAN_B)   // 98

typedef _Float16 h8 __attribute__((ext_vector_type(8)));
typedef _Float16 h4 __attribute__((ext_vector_type(4)));
typedef float    f4 __attribute__((ext_vector_type(4)));

struct __align__(16) H8 { __half2 v[4]; };   // 8 fp16 = 16 B
struct __align__(8)  Hq { __half2 a, b; };   // 4 fp16 = 8 B

// ---------------------------------------------------------------------------
// CSR build: histogram of dst, inclusive scan, scatter edge ids.
// ---------------------------------------------------------------------------
__global__ __launch_bounds__(256) void hist_kernel(
    const int* __restrict__ dst, int* __restrict__ counts, int n_edges)
{
    int e = blockIdx.x * 256 + threadIdx.x;
    if (e < n_edges) atomicAdd(&counts[dst[e]], 1);
}

__global__ __launch_bounds__(SCAN_B) void scan1_kernel(
    const int* __restrict__ counts, int* __restrict__ incl,
    int* __restrict__ blocksums, int n)
{
    __shared__ int sdata[SCAN_B];
    const int lid = threadIdx.x;
    const int i = blockIdx.x * SCAN_B + lid;
    sdata[lid] = (i < n) ? counts[i] : 0;
    __syncthreads();
#pragma unroll
    for (int off = 1; off < SCAN_B; off <<= 1) {
        int t = (lid >= off) ? sdata[lid - off] : 0;
        __syncthreads();
        sdata[lid] += t;
        __syncthreads();
    }
    if (i < n) incl[i] = sdata[lid];
    if (lid == SCAN_B - 1) blocksums[blockIdx.x] = sdata[lid];
}

__global__ void scan2_kernel(const int* __restrict__ blocksums,
                             int* __restrict__ blockoffs, int nb)
{
    if (threadIdx.x == 0 && blockIdx.x == 0) {
        int off = 0;
        for (int b = 0; b < nb; ++b) { blockoffs[b] = off; off += blocksums[b]; }
    }
}

__global__ __launch_bounds__(SCAN_B) void scan3_kernel(
    int* __restrict__ incl, const int* __restrict__ blockoffs, int n)
{
    const int i = blockIdx.x * SCAN_B + threadIdx.x;
    if (i < n) incl[i] += blockoffs[blockIdx.x];
}

__global__ __launch_bounds__(256) void initrows_kernel(
    const int* __restrict__ incl, const int* __restrict__ counts,
    int* __restrict__ rowstart, int* __restrict__ cursor, int n)
{
    const int i = blockIdx.x * 256 + threadIdx.x;
    if (i < n) {
        const int rs = incl[i] - counts[i];
        rowstart[i] = rs;
        cursor[i]   = rs;
    }
}

__global__ __launch_bounds__(256) void scatter_kernel(
    const int* __restrict__ src, const int* __restrict__ dst,
    int* __restrict__ cursor, int* __restrict__ perm_src,
    int* __restrict__ perm_eid, int n_edges)
{
    const int e = blockIdx.x * 256 + threadIdx.x;
    if (e < n_edges) {
        const int pos = atomicAdd(&cursor[dst[e]], 1);
        perm_src[pos] = src[e];
        perm_eid[pos] = e;
    }
}

// Gather edge_attr rows into CSR order AND convert to fp16 pairs.
__global__ __launch_bounds__(256) void permute_ea_f16_kernel(
    const float* __restrict__ edge_attr, const int* __restrict__ perm_eid,
    __half* __restrict__ ea_f16, int n_edges)
{
    const int j = blockIdx.x * 256 + threadIdx.x;
    if (j >= n_edges) return;
    const int eid = perm_eid[j];
    const float4* p = (const float4*)(edge_attr + (size_t)eid * 16);
    const float4 q0 = p[0], q1 = p[1], q2 = p[2], q3 = p[3];
    H8 a, b;
    a.v[0] = __floats2half2_rn(q0.x, q0.y);
    a.v[1] = __floats2half2_rn(q0.z, q0.w);
    a.v[2] = __floats2half2_rn(q1.x, q1.y);
    a.v[3] = __floats2half2_rn(q1.z, q1.w);
    b.v[0] = __floats2half2_rn(q2.x, q2.y);
    b.v[1] = __floats2half2_rn(q2.z, q2.w);
    b.v[2] = __floats2half2_rn(q3.x, q3.y);
    b.v[3] = __floats2half2_rn(q3.z, q3.w);
    H8* o = (H8*)(ea_f16 + (size_t)j * 16);
    o[0] = a;
    o[1] = b;
}

// Cast fp32 array -> f16 (vectorized by 4).
__global__ __launch_bounds__(256) void cast_f16_kernel(
    const float* __restrict__ in, _Float16* __restrict__ out, int n4)
{
    const int i = blockIdx.x * 256 + threadIdx.x;
    if (i >= n4) return;
    const float4 v = ((const float4*)in)[i];
    h4 o; o[0] = (_Float16)v.x; o[1] = (_Float16)v.y;
    o[2] = (_Float16)v.z; o[3] = (_Float16)v.w;
    *(h4*)(out + (size_t)i * 4) = o;
}

// Transpose + cast weights: wt[n][k] = (f16) w[k][n].  (tiny, one-time)
__global__ __launch_bounds__(256) void transpose_w_kernel(
    const float* __restrict__ w, _Float16* __restrict__ wt, int K, int N)
{
    const int i = blockIdx.x * 256 + threadIdx.x;
    if (i >= K * N) return;
    const int n = i / K;
    const int k = i - n * K;
    wt[(size_t)n * K + k] = (_Float16)w[(size_t)k * N + n];
}

// ---------------------------------------------------------------------------
// CSR aggregate, quad-per-lane + packed-fp16 edge MLP + f16 h-gather.
// Per edge per lane: 2 VMEM (ea) + 1 dwordx2 (h f16) + 32 v_pk_fma_f16.
// ---------------------------------------------------------------------------
__device__ __forceinline__ float4 eamlp_f16(const H8* __restrict__ p,
                                            const __half2 (*ew2)[4],
                                            const float4 ebv)
{
    const H8 a = p[0], b = p[1];
    __half2 c0 = {0.f, 0.f}, c1 = {0.f, 0.f}, c2 = {0.f, 0.f}, c3 = {0.f, 0.f};
#pragma unroll
    for (int k2 = 0; k2 < 4; ++k2) {
        c0 = __hfma2(a.v[k2], ew2[k2][0], c0);
        c1 = __hfma2(a.v[k2], ew2[k2][1], c1);
        c2 = __hfma2(a.v[k2], ew2[k2][2], c2);
        c3 = __hfma2(a.v[k2], ew2[k2][3], c3);
    }
#pragma unroll
    for (int k2 = 0; k2 < 4; ++k2) {
        c0 = __hfma2(b.v[k2], ew2[4 + k2][0], c0);
        c1 = __hfma2(b.v[k2], ew2[4 + k2][1], c1);
        c2 = __hfma2(b.v[k2], ew2[4 + k2][2], c2);
        c3 = __hfma2(b.v[k2], ew2[4 + k2][3], c3);
    }
    float4 m;
    m.x = ebv.x + __low2float(c0) + __high2float(c0);
    m.y = ebv.y + __low2float(c1) + __high2float(c1);
    m.z = ebv.z + __low2float(c2) + __high2float(c2);
    m.w = ebv.w + __low2float(c3) + __high2float(c3);
    return m;
}

template<int DIN>
__global__ __launch_bounds__(256) void gine_agg_kernel(
    const __half* __restrict__ h16, const __half* __restrict__ ea_f16,
    const int* __restrict__ perm_src,
    const int* __restrict__ rowstart, const int* __restrict__ rowend,
    const float* __restrict__ ew, const float* __restrict__ eb,
    float* __restrict__ agg, int n_nodes)
{
    constexpr int NQ    = DIN / 4;
    constexpr int SLOTS = 256 / NQ;
    const int fq   = threadIdx.x & (NQ - 1);
    const int slot = threadIdx.x / NQ;
    const int v = blockIdx.x * SLOTS + slot;
    if (v >= n_nodes) return;

    __half2 ew2[8][4];
#pragma unroll
    for (int k2 = 0; k2 < 8; ++k2)
#pragma unroll
        for (int fi = 0; fi < 4; ++fi)
            ew2[k2][fi] = __floats2half2_rn(ew[(size_t)(2 * k2)     * DIN + fq * 4 + fi],
                                            ew[(size_t)(2 * k2 + 1) * DIN + fq * 4 + fi]);
    const float4 ebv = *(const float4*)(eb + fq * 4);

    const int s0 = rowstart[v];
    const int s1 = rowend[v];

    float4 acc = {0.f, 0.f, 0.f, 0.f};
    int j = s0;
    for (; j + 2 <= s1; j += 2) {
        const int sn0 = perm_src[j + 0];
        const int sn1 = perm_src[j + 1];
        const Hq hq0 = *(const Hq*)(h16 + (size_t)sn0 * DIN + fq * 4);
        const Hq hq1 = *(const Hq*)(h16 + (size_t)sn1 * DIN + fq * 4);
        const H8* p0 = (const H8*)(ea_f16 + (size_t)(j + 0) * 16);
        const H8* p1 = (const H8*)(ea_f16 + (size_t)(j + 1) * 16);
        const float4 m0 = eamlp_f16(p0, ew2, ebv);
        const float4 m1 = eamlp_f16(p1, ew2, ebv);
        const float2 l0 = __half22float2(hq0.a), u0 = __half22float2(hq0.b);
        const float2 l1 = __half22float2(hq1.a), u1 = __half22float2(hq1.b);
        acc.x += fmaxf(m0.x + l0.x, 0.f) + fmaxf(m1.x + l1.x, 0.f);
        acc.y += fmaxf(m0.y + l0.y, 0.f) + fmaxf(m1.y + l1.y, 0.f);
        acc.z += fmaxf(m0.z + u0.x, 0.f) + fmaxf(m1.z + u1.x, 0.f);
        acc.w += fmaxf(m0.w + u0.y, 0.f) + fmaxf(m1.w + u1.y, 0.f);
    }
    if (j < s1) {
        const int sn = perm_src[j];
        const Hq hq = *(const Hq*)(h16 + (size_t)sn * DIN + fq * 4);
        const H8* p = (const H8*)(ea_f16 + (size_t)j * 16);
        const float4 m = eamlp_f16(p, ew2, ebv);
        const float2 l = __half22float2(hq.a), u = __half22float2(hq.b);
        acc.x += fmaxf(m.x + l.x, 0.f);
        acc.y += fmaxf(m.y + l.y, 0.f);
        acc.z += fmaxf(m.z + u.x, 0.f);
        acc.w += fmaxf(m.w + u.y, 0.f);
    }
    *(float4*)(agg + (size_t)v * DIN + fq * 4) = acc;
}

// ---------------------------------------------------------------------------
// Node kernel v4 (MFMA f16): block = 4 waves, 16 nodes per wave.
// mm1: A = f16(h+agg) tile (LDS, +8 pad), B = W1T f16 (global, L2-hot);
// BN+relu in f32 regs -> s_t f16 -> mm2 -> relu -> hout f32 + h16 mirror.
// A layout: A[m=lane&15][k=quad*8+j]; B[k][n]: n=lane&15, k=quad*8+j;
// C/D: col=lane&15, row=quad*4+reg (per cdna_hip_programming.md §3).
// ---------------------------------------------------------------------------
template<int DIN>
__global__ __launch_bounds__(256) void node_mfma_kernel(
    const float* __restrict__ h, const float* __restrict__ agg,
    const _Float16* __restrict__ w1t, const float* __restrict__ b1,
    const float* __restrict__ gm, const float* __restrict__ bt,
    const _Float16* __restrict__ w2t, const float* __restrict__ b2,
    float* __restrict__ hout, _Float16* __restrict__ h16out, int n_tiles)
{
    constexpr int SXP = DIN + 8;
    constexpr int STP = HID_C + 8;
    __shared__ _Float16 s_x[4][16][SXP];
    __shared__ _Float16 s_t[4][16][STP];

    const int w    = threadIdx.x >> 6;
    const int lane = threadIdx.x & 63;
    int tile = blockIdx.x * 4 + w;
    if (tile >= n_tiles) tile = n_tiles - 1;   // clamp: keep barriers uniform
    const int node0 = tile * 16;

    // ---- stage X = h + agg -> f16 LDS tile ----
    constexpr int KQ = DIN / 4;
    for (int it = lane; it < 16 * KQ; it += 64) {
        const int ni = it / KQ;
        const int k4 = (it - ni * KQ) * 4;
        const float4 hv = *(const float4*)(h   + (size_t)(node0 + ni) * DIN + k4);
        const float4 av = *(const float4*)(agg + (size_t)(node0 + ni) * DIN + k4);
        h4 o;
        o[0] = (_Float16)(hv.x + av.x);
        o[1] = (_Float16)(hv.y + av.y);
        o[2] = (_Float16)(hv.z + av.z);
        o[3] = (_Float16)(hv.w + av.w);
        *(h4*)&s_x[w][ni][k4] = o;
    }
    __syncthreads();

    const int ln   = lane & 15;
    const int quad = lane >> 4;

    // ---- mm1 + BN + relu -> s_t (f16) ----
#pragma unroll
    for (int nt = 0; nt < 8; ++nt) {
        const int col = nt * 16 + ln;
        const float bv = b1[col];
        f4 acc = {bv, bv, bv, bv};
#pragma unroll
        for (int ks = 0; ks < DIN / 32; ++ks) {
            const h8 af = *(const h8*)&s_x[w][ln][ks * 32 + quad * 8];
            const h8 bf = *(const h8*)(w1t + (size_t)col * DIN + ks * 32 + quad * 8);
            acc = __builtin_amdgcn_mfma_f32_16x16x32_f16(af, bf, acc, 0, 0, 0);
        }
        const float gv = gm[col], btv = bt[col];
#pragma unroll
        for (int r = 0; r < 4; ++r) {
            const float t = fmaxf(fmaf(acc[r] * BN_SCALE_C, gv, btv), 0.f);
            s_t[w][quad * 4 + r][col] = (_Float16)t;
        }
    }
    __syncthreads();

    // ---- mm2 + relu -> hout f32 + h16 mirror ----
#pragma unroll
    for (int nt = 0; nt < 8; ++nt) {
        const int col = nt * 16 + ln;
        const float bv = b2[col];
        f4 acc = {bv, bv, bv, bv};
#pragma unroll
        for (int ks = 0; ks < HID_C / 32; ++ks) {
            const h8 af = *(const h8*)&s_t[w][ln][ks * 32 + quad * 8];
            const h8 bf = *(const h8*)(w2t + (size_t)col * HID_C + ks * 32 + quad * 8);
            acc = __builtin_amdgcn_mfma_f32_16x16x32_f16(af, bf, acc, 0, 0, 0);
        }
#pragma unroll
        for (int r = 0; r < 4; ++r) {
            const int node = node0 + quad * 4 + r;
            const float v = fmaxf(acc[r], 0.f);
            hout[(size_t)node * HID_C + col] = v;
            h16out[(size_t)node * HID_C + col] = (_Float16)v;
        }
    }
}

// ---------------------------------------------------------------------------
// Pool + output MLP (unchanged).
// ---------------------------------------------------------------------------
__global__ __launch_bounds__(256) void pool_kernel(
    const float* __restrict__ hfin, const int* __restrict__ batch,
    const float* __restrict__ w1, const float* __restrict__ b1,
    const float* __restrict__ w2, const float* __restrict__ b2,
    float* __restrict__ out, int n_nodes)
{
    const int gid = blockIdx.x;

    int lo = 0, hi = n_nodes;
    while (lo < hi) { int mid = (lo + hi) >> 1; if (batch[mid] < gid) lo = mid + 1; else hi = mid; }
    const int start = lo;
    hi = n_nodes;
    while (lo < hi) { int mid = (lo + hi) >> 1; if (batch[mid] < gid + 1) lo = mid + 1; else hi = mid; }
    const int end = lo;

    const int f = threadIdx.x & (HID_C - 1);
    const int half = threadIdx.x >> 7;

    float sum = 0.f;
    for (int n = start + half; n < end; n += 2)
        sum += hfin[(size_t)n * HID_C + f];

    __shared__ float s_sum[2][HID_C];
    __shared__ float s_p[HID_C];
    __shared__ float s_t[HID_C];
    s_sum[half][f] = sum;
    __syncthreads();

    if (threadIdx.x < HID_C) {
        const float cnt = (float)(end - start);
        s_p[f] = (s_sum[0][f] + s_sum[1][f]) / fmaxf(cnt, 1.f);
    }
    __syncthreads();

    if (threadIdx.x < HID_C) {
        float acc = b1[f];
        for (int k = 0; k < HID_C; ++k) acc = fmaf(s_p[k], w1[k * HID_C + f], acc);
        s_t[f] = fmaxf(acc, 0.f);
    }
    __syncthreads();

    if (threadIdx.x < HID_C) {
        float acc = b2[f];
        for (int k = 0; k < HID_C; ++k) acc = fmaf(s_t[k], w2[k * HID_C + f], acc);
        out[(size_t)gid * HID_C + f] = acc;
    }
}

// ---------------------------------------------------------------------------
extern "C" void kernel_launch(void* const* d_in, const int* in_sizes, int n_in,
                              void* d_out, int out_size, void* d_ws, size_t ws_size,
                              hipStream_t stream)
{
    const float* x         = (const float*)d_in[0];
    const float* edge_attr = (const float*)d_in[1];
    const int*   edge_index= (const int*)  d_in[2];
    const int*   batch     = (const int*)  d_in[3];
    const int*   src = edge_index;
    const int*   dst = edge_index + N_EDGES_C;

    const float* el_w[3] = {(const float*)d_in[4],  (const float*)d_in[12], (const float*)d_in[20]};
    const float* el_b[3] = {(const float*)d_in[5],  (const float*)d_in[13], (const float*)d_in[21]};
    const float* c_w1[3] = {(const float*)d_in[6],  (const float*)d_in[14], (const float*)d_in[22]};
    const float* c_b1[3] = {(const float*)d_in[7],  (const float*)d_in[15], (const float*)d_in[23]};
    const float* c_g [3] = {(const float*)d_in[8],  (const float*)d_in[16], (const float*)d_in[24]};
    const float* c_bt[3] = {(const float*)d_in[9],  (const float*)d_in[17], (const float*)d_in[25]};
    const float* c_w2[3] = {(const float*)d_in[10], (const float*)d_in[18], (const float*)d_in[26]};
    const float* c_b2[3] = {(const float*)d_in[11], (const float*)d_in[19], (const float*)d_in[27]};
    const float* o_w1 = (const float*)d_in[28];
    const float* o_b1 = (const float*)d_in[29];
    const float* o_w2 = (const float*)d_in[30];
    const float* o_b2 = (const float*)d_in[31];

    // ---- workspace layout (~207 MB; round 3 proved ws >= 220 MB) ----
    char* wsp = (char*)d_ws;
    size_t used = 0;
    auto alloc = [&](size_t bytes) { char* p = wsp + used; used += (bytes + 255) & ~(size_t)255; return p; };
    float* h        = (float*)alloc((size_t)N_NODES_C * HID_C * 4);
    float* agg      = (float*)alloc((size_t)N_NODES_C * HID_C * 4);
    int*   counts   = (int*)alloc((size_t)N_NODES_C * 4);
    int*   incl     = (int*)alloc((size_t)N_NODES_C * 4);
    int*   rowstart = (int*)alloc((size_t)N_NODES_C * 4);
    int*   cursor   = (int*)alloc((size_t)N_NODES_C * 4);
    int*   blocksums= (int*)alloc(128 * 4);
    int*   blockoffs= (int*)alloc(128 * 4);
    int*   perm_src = (int*)alloc((size_t)N_EDGES_C * 4);
    int*   perm_eid = (int*)alloc((size_t)N_EDGES_C * 4);
    __half*    ea_f16 = (__half*)alloc((size_t)N_EDGES_C * 16 * 2);
    _Float16*  h_f16  = (_Float16*)alloc((size_t)N_NODES_C * HID_C * 2);
    _Float16*  x_f16  = (_Float16*)alloc((size_t)N_NODES_C * 64 * 2);
    _Float16*  w1t[3], *w2t[3];
    for (int l = 0; l < 3; ++l) {
        w1t[l] = (_Float16*)alloc((size_t)HID_C * HID_C * 2);
        w2t[l] = (_Float16*)alloc((size_t)HID_C * HID_C * 2);
    }
    (void)ws_size;

    // ---- CSR build (once; reused by all 3 layers) ----
    hipMemsetAsync(counts, 0, (size_t)N_NODES_C * 4, stream);
    hist_kernel<<<(N_EDGES_C + 255) / 256, 256, 0, stream>>>(dst, counts, N_EDGES_C);
    scan1_kernel<<<SCAN_NB, SCAN_B, 0, stream>>>(counts, incl, blocksums, N_NODES_C);
    scan2_kernel<<<1, 64, 0, stream>>>(blocksums, blockoffs, SCAN_NB);
    scan3_kernel<<<SCAN_NB, SCAN_B, 0, stream>>>(incl, blockoffs, N_NODES_C);
    initrows_kernel<<<(N_NODES_C + 255) / 256, 256, 0, stream>>>(incl, counts, rowstart,
                                                                 cursor, N_NODES_C);
    scatter_kernel<<<(N_EDGES_C + 255) / 256, 256, 0, stream>>>(src, dst, cursor,
                                                                perm_src, perm_eid, N_EDGES_C);
    permute_ea_f16_kernel<<<(N_EDGES_C + 255) / 256, 256, 0, stream>>>(
        edge_attr, perm_eid, ea_f16, N_EDGES_C);
    cast_f16_kernel<<<(N_NODES_C * 64 / 4 + 255) / 256, 256, 0, stream>>>(
        x, x_f16, N_NODES_C * 64 / 4);
    for (int l = 0; l < 3; ++l) {
        const int K1 = (l == 0) ? 64 : HID_C;
        transpose_w_kernel<<<(K1 * HID_C + 255) / 256, 256, 0, stream>>>(
            c_w1[l], w1t[l], K1, HID_C);
        transpose_w_kernel<<<(HID_C * HID_C + 255) / 256, 256, 0, stream>>>(
            c_w2[l], w2t[l], HID_C, HID_C);
    }

    const int n_tiles = N_NODES_C / 16;            // 6250
    const int nb_node = (n_tiles + 3) / 4;         // 1563

    // ---- 3 GINE layers ----
    for (int l = 0; l < 3; ++l) {
        if (l == 0) {
            gine_agg_kernel<64><<<(N_NODES_C + 15) / 16, 256, 0, stream>>>(
                (const __half*)x_f16, ea_f16, perm_src, rowstart, incl,
                el_w[0], el_b[0], agg, N_NODES_C);
            node_mfma_kernel<64><<<nb_node, 256, 0, stream>>>(
                x, agg, w1t[0], c_b1[0], c_g[0], c_bt[0], w2t[0], c_b2[0],
                h, h_f16, n_tiles);
        } else {
            gine_agg_kernel<128><<<(N_NODES_C + 7) / 8, 256, 0, stream>>>(
                (const __half*)h_f16, ea_f16, perm_src, rowstart, incl,
                el_w[l], el_b[l], agg, N_NODES_C);
            node_mfma_kernel<128><<<nb_node, 256, 0, stream>>>(
                h, agg, w1t[l], c_b1[l], c_g[l], c_bt[l], w2t[l], c_b2[l],
                h, h_f16, n_tiles);
        }
    }

    // ---- pool + output MLP ----
    pool_kernel<<<N_GRAPHS_C, 256, 0, stream>>>(h, batch, o_w1, o_b1, o_w2, o_b2,
                                                (float*)d_out, N_NODES_C);
}

// Round 2
// 1047.640 us; speedup vs baseline: 1.0631x; 1.0631x over previous
//
#include <hip/hip_runtime.h>
#include <hip/hip_fp16.h>
#include <cstdint>
#include <cstddef>

#define N_NODES_C  100000
#define N_EDGES_C  1600000
#define N_GRAPHS_C 256
#define HID_C      128
// 1/sqrt(1+1e-5)
#define BN_SCALE_C 0.9999950000374997f

#define SCAN_B 1024
#define SCAN_NB ((N_NODES_C + SCAN_B - 1) / SCAN_B)   // 98

typedef _Float16 h2 __attribute__((ext_vector_type(2)));
typedef _Float16 h4 __attribute__((ext_vector_type(4)));
typedef _Float16 h8 __attribute__((ext_vector_type(8)));
typedef float    f4 __attribute__((ext_vector_type(4)));

struct __align__(16) EA8 { h2 p[4]; };   // 8 fp16 = 16 B
struct __align__(8)  HQ  { h2 a, b; };   // 4 fp16 = 8 B
struct __align__(16) H8 { __half2 v[4]; };   // for preamble convert

// v_dot2_f32_f16: f32 += a.x*b.x + a.y*b.y  (f32 accumulate, no unpack)
#if defined(__has_builtin)
#  if __has_builtin(__builtin_amdgcn_fdot2)
#    define HAVE_FDOT2 1
#  endif
#endif
#ifndef HAVE_FDOT2
#  define HAVE_FDOT2 0
#endif

__device__ __forceinline__ float fdot2_(h2 a, h2 b, float c)
{
#if HAVE_FDOT2
    return __builtin_amdgcn_fdot2(a, b, c, false);
#else
    return c + (float)a[0] * (float)b[0] + (float)a[1] * (float)b[1];
#endif
}

// ---------------------------------------------------------------------------
// CSR build: histogram of dst, inclusive scan, scatter edge ids.
// ---------------------------------------------------------------------------
__global__ __launch_bounds__(256) void hist_kernel(
    const int* __restrict__ dst, int* __restrict__ counts, int n_edges)
{
    int e = blockIdx.x * 256 + threadIdx.x;
    if (e < n_edges) atomicAdd(&counts[dst[e]], 1);
}

__global__ __launch_bounds__(SCAN_B) void scan1_kernel(
    const int* __restrict__ counts, int* __restrict__ incl,
    int* __restrict__ blocksums, int n)
{
    __shared__ int sdata[SCAN_B];
    const int lid = threadIdx.x;
    const int i = blockIdx.x * SCAN_B + lid;
    sdata[lid] = (i < n) ? counts[i] : 0;
    __syncthreads();
#pragma unroll
    for (int off = 1; off < SCAN_B; off <<= 1) {
        int t = (lid >= off) ? sdata[lid - off] : 0;
        __syncthreads();
        sdata[lid] += t;
        __syncthreads();
    }
    if (i < n) incl[i] = sdata[lid];
    if (lid == SCAN_B - 1) blocksums[blockIdx.x] = sdata[lid];
}

__global__ void scan2_kernel(const int* __restrict__ blocksums,
                             int* __restrict__ blockoffs, int nb)
{
    if (threadIdx.x == 0 && blockIdx.x == 0) {
        int off = 0;
        for (int b = 0; b < nb; ++b) { blockoffs[b] = off; off += blocksums[b]; }
    }
}

__global__ __launch_bounds__(SCAN_B) void scan3_kernel(
    int* __restrict__ incl, const int* __restrict__ blockoffs, int n)
{
    const int i = blockIdx.x * SCAN_B + threadIdx.x;
    if (i < n) incl[i] += blockoffs[blockIdx.x];
}

__global__ __launch_bounds__(256) void initrows_kernel(
    const int* __restrict__ incl, const int* __restrict__ counts,
    int* __restrict__ rowstart, int* __restrict__ cursor, int n)
{
    const int i = blockIdx.x * 256 + threadIdx.x;
    if (i < n) {
        const int rs = incl[i] - counts[i];
        rowstart[i] = rs;
        cursor[i]   = rs;
    }
}

__global__ __launch_bounds__(256) void scatter_kernel(
    const int* __restrict__ src, const int* __restrict__ dst,
    int* __restrict__ cursor, int* __restrict__ perm_src,
    int* __restrict__ perm_eid, int n_edges)
{
    const int e = blockIdx.x * 256 + threadIdx.x;
    if (e < n_edges) {
        const int pos = atomicAdd(&cursor[dst[e]], 1);
        perm_src[pos] = src[e];
        perm_eid[pos] = e;
    }
}

// Gather edge_attr rows into CSR order AND convert to fp16 pairs.
__global__ __launch_bounds__(256) void permute_ea_f16_kernel(
    const float* __restrict__ edge_attr, const int* __restrict__ perm_eid,
    __half* __restrict__ ea_f16, int n_edges)
{
    const int j = blockIdx.x * 256 + threadIdx.x;
    if (j >= n_edges) return;
    const int eid = perm_eid[j];
    const float4* p = (const float4*)(edge_attr + (size_t)eid * 16);
    const float4 q0 = p[0], q1 = p[1], q2 = p[2], q3 = p[3];
    H8 a, b;
    a.v[0] = __floats2half2_rn(q0.x, q0.y);
    a.v[1] = __floats2half2_rn(q0.z, q0.w);
    a.v[2] = __floats2half2_rn(q1.x, q1.y);
    a.v[3] = __floats2half2_rn(q1.z, q1.w);
    b.v[0] = __floats2half2_rn(q2.x, q2.y);
    b.v[1] = __floats2half2_rn(q2.z, q2.w);
    b.v[2] = __floats2half2_rn(q3.x, q3.y);
    b.v[3] = __floats2half2_rn(q3.z, q3.w);
    H8* o = (H8*)(ea_f16 + (size_t)j * 16);
    o[0] = a;
    o[1] = b;
}

// Cast fp32 array -> f16 (vectorized by 4).
__global__ __launch_bounds__(256) void cast_f16_kernel(
    const float* __restrict__ in, _Float16* __restrict__ out, int n4)
{
    const int i = blockIdx.x * 256 + threadIdx.x;
    if (i >= n4) return;
    const float4 v = ((const float4*)in)[i];
    h4 o; o[0] = (_Float16)v.x; o[1] = (_Float16)v.y;
    o[2] = (_Float16)v.z; o[3] = (_Float16)v.w;
    *(h4*)(out + (size_t)i * 4) = o;
}

// Transpose + cast weights: wt[n][k] = (f16) w[k][n].  (tiny, one-time)
__global__ __launch_bounds__(256) void transpose_w_kernel(
    const float* __restrict__ w, _Float16* __restrict__ wt, int K, int N)
{
    const int i = blockIdx.x * 256 + threadIdx.x;
    if (i >= K * N) return;
    const int n = i / K;
    const int k = i - n * K;
    wt[(size_t)n * K + k] = (_Float16)w[(size_t)k * N + n];
}

// ---------------------------------------------------------------------------
// Fused GINE layer: per wave, phase 1 aggregates a 16-node tile into the
// s_x LDS tile (CSR edge loop, fdot2 edge-MLP, residual from f16 h), then
// phase 2 runs mm1(BN,relu) + mm2(relu) with MFMA, writing the f16 mirror
// (and f32 h only on the last layer, for the pool kernel).
// Saves: agg f32 write+read (102 MB/layer) + h f32 read (51 MB/layer) +
// hout f32 writes on non-final layers.
// ---------------------------------------------------------------------------
template<int DIN, bool LASTL>
__global__ __launch_bounds__(128) void gine_layer_kernel(
    const _Float16* __restrict__ hin,     // [N][DIN] f16 (gather + residual)
    const _Float16* __restrict__ ea16,    // [E][16] f16, CSR order
    const int* __restrict__ perm_src,
    const int* __restrict__ rowstart, const int* __restrict__ rowend,
    const float* __restrict__ ew, const float* __restrict__ eb,
    const _Float16* __restrict__ w1t, const float* __restrict__ b1,
    const float* __restrict__ gm, const float* __restrict__ bt,
    const _Float16* __restrict__ w2t, const float* __restrict__ b2,
    float* __restrict__ hout, _Float16* __restrict__ h16out, int n_tiles)
{
    constexpr int SXP = DIN + 8;
    constexpr int STP = HID_C + 8;
    __shared__ _Float16 s_x[2][16][SXP];
    __shared__ _Float16 s_t[2][16][STP];

    const int w    = threadIdx.x >> 6;
    const int lane = threadIdx.x & 63;
    int tile = blockIdx.x * 2 + w;
    if (tile >= n_tiles) tile = n_tiles - 1;   // clamp: keep barriers uniform
    const int node0 = tile * 16;

    // ---- phase 1: CSR aggregate + residual -> s_x (f16) ----
    constexpr int NQ  = DIN / 4;    // lanes per node (32 or 16)
    constexpr int GPW = 64 / NQ;    // node-groups per wave (2 or 4)
    constexpr int NPG = 16 / GPW;   // nodes per group (8 or 4)
    const int fq = lane & (NQ - 1);
    const int g  = lane / NQ;

    // edge-MLP weights as f16 pairs: ew2h[k2][fi] = (ew[2k2][f], ew[2k2+1][f])
    h2 ew2h[8][4];
#pragma unroll
    for (int k2 = 0; k2 < 8; ++k2)
#pragma unroll
        for (int fi = 0; fi < 4; ++fi) {
            h2 t;
            t[0] = (_Float16)ew[(size_t)(2 * k2)     * DIN + fq * 4 + fi];
            t[1] = (_Float16)ew[(size_t)(2 * k2 + 1) * DIN + fq * 4 + fi];
            ew2h[k2][fi] = t;
        }
    const float4 ebv = *(const float4*)(eb + fq * 4);

#pragma unroll
    for (int i = 0; i < NPG; ++i) {
        const int ni = g * NPG + i;
        const int v  = node0 + ni;
        const int s0 = rowstart[v];
        const int s1 = rowend[v];

        float4 acc = {0.f, 0.f, 0.f, 0.f};
        int j = s0;
        for (; j + 2 <= s1; j += 2) {
            const int sn0 = perm_src[j + 0];
            const int sn1 = perm_src[j + 1];
            const HQ hq0 = *(const HQ*)(hin + (size_t)sn0 * DIN + fq * 4);
            const HQ hq1 = *(const HQ*)(hin + (size_t)sn1 * DIN + fq * 4);
            const EA8* pe = (const EA8*)(ea16 + (size_t)j * 16);
            const EA8 a0 = pe[0], c0 = pe[1], a1 = pe[2], c1 = pe[3];
            float4 m0 = {ebv.x, ebv.y, ebv.z, ebv.w};
            float4 m1 = m0;
#pragma unroll
            for (int k = 0; k < 4; ++k) {
                m0.x = fdot2_(a0.p[k], ew2h[k][0], m0.x);
                m0.y = fdot2_(a0.p[k], ew2h[k][1], m0.y);
                m0.z = fdot2_(a0.p[k], ew2h[k][2], m0.z);
                m0.w = fdot2_(a0.p[k], ew2h[k][3], m0.w);
                m1.x = fdot2_(a1.p[k], ew2h[k][0], m1.x);
                m1.y = fdot2_(a1.p[k], ew2h[k][1], m1.y);
                m1.z = fdot2_(a1.p[k], ew2h[k][2], m1.z);
                m1.w = fdot2_(a1.p[k], ew2h[k][3], m1.w);
            }
#pragma unroll
            for (int k = 0; k < 4; ++k) {
                m0.x = fdot2_(c0.p[k], ew2h[4 + k][0], m0.x);
                m0.y = fdot2_(c0.p[k], ew2h[4 + k][1], m0.y);
                m0.z = fdot2_(c0.p[k], ew2h[4 + k][2], m0.z);
                m0.w = fdot2_(c0.p[k], ew2h[4 + k][3], m0.w);
                m1.x = fdot2_(c1.p[k], ew2h[4 + k][0], m1.x);
                m1.y = fdot2_(c1.p[k], ew2h[4 + k][1], m1.y);
                m1.z = fdot2_(c1.p[k], ew2h[4 + k][2], m1.z);
                m1.w = fdot2_(c1.p[k], ew2h[4 + k][3], m1.w);
            }
            acc.x += fmaxf(m0.x + (float)hq0.a[0], 0.f) + fmaxf(m1.x + (float)hq1.a[0], 0.f);
            acc.y += fmaxf(m0.y + (float)hq0.a[1], 0.f) + fmaxf(m1.y + (float)hq1.a[1], 0.f);
            acc.z += fmaxf(m0.z + (float)hq0.b[0], 0.f) + fmaxf(m1.z + (float)hq1.b[0], 0.f);
            acc.w += fmaxf(m0.w + (float)hq0.b[1], 0.f) + fmaxf(m1.w + (float)hq1.b[1], 0.f);
        }
        if (j < s1) {
            const int sn = perm_src[j];
            const HQ hq = *(const HQ*)(hin + (size_t)sn * DIN + fq * 4);
            const EA8* pe = (const EA8*)(ea16 + (size_t)j * 16);
            const EA8 a0 = pe[0], c0 = pe[1];
            float4 m0 = {ebv.x, ebv.y, ebv.z, ebv.w};
#pragma unroll
            for (int k = 0; k < 4; ++k) {
                m0.x = fdot2_(a0.p[k], ew2h[k][0], m0.x);
                m0.y = fdot2_(a0.p[k], ew2h[k][1], m0.y);
                m0.z = fdot2_(a0.p[k], ew2h[k][2], m0.z);
                m0.w = fdot2_(a0.p[k], ew2h[k][3], m0.w);
            }
#pragma unroll
            for (int k = 0; k < 4; ++k) {
                m0.x = fdot2_(c0.p[k], ew2h[4 + k][0], m0.x);
                m0.y = fdot2_(c0.p[k], ew2h[4 + k][1], m0.y);
                m0.z = fdot2_(c0.p[k], ew2h[4 + k][2], m0.z);
                m0.w = fdot2_(c0.p[k], ew2h[4 + k][3], m0.w);
            }
            acc.x += fmaxf(m0.x + (float)hq.a[0], 0.f);
            acc.y += fmaxf(m0.y + (float)hq.a[1], 0.f);
            acc.z += fmaxf(m0.z + (float)hq.b[0], 0.f);
            acc.w += fmaxf(m0.w + (float)hq.b[1], 0.f);
        }

        // residual (f16 mirror of h) + write x = h + agg to LDS
        const HQ hv = *(const HQ*)(hin + (size_t)v * DIN + fq * 4);
        h4 o;
        o[0] = (_Float16)(acc.x + (float)hv.a[0]);
        o[1] = (_Float16)(acc.y + (float)hv.a[1]);
        o[2] = (_Float16)(acc.z + (float)hv.b[0]);
        o[3] = (_Float16)(acc.w + (float)hv.b[1]);
        *(h4*)&s_x[w][ni][fq * 4] = o;
    }
    __syncthreads();

    const int ln   = lane & 15;
    const int quad = lane >> 4;

    // ---- phase 2a: mm1 + BN + relu -> s_t (f16) ----
#pragma unroll
    for (int nt = 0; nt < 8; ++nt) {
        const int col = nt * 16 + ln;
        const float bv = b1[col];
        f4 acc = {bv, bv, bv, bv};
#pragma unroll
        for (int ks = 0; ks < DIN / 32; ++ks) {
            const h8 af = *(const h8*)&s_x[w][ln][ks * 32 + quad * 8];
            const h8 bf = *(const h8*)(w1t + (size_t)col * DIN + ks * 32 + quad * 8);
            acc = __builtin_amdgcn_mfma_f32_16x16x32_f16(af, bf, acc, 0, 0, 0);
        }
        const float gv = gm[col], btv = bt[col];
#pragma unroll
        for (int r = 0; r < 4; ++r) {
            const float t = fmaxf(fmaf(acc[r] * BN_SCALE_C, gv, btv), 0.f);
            s_t[w][quad * 4 + r][col] = (_Float16)t;
        }
    }
    __syncthreads();

    // ---- phase 2b: mm2 + relu -> h16 mirror (or f32 h on last layer) ----
#pragma unroll
    for (int nt = 0; nt < 8; ++nt) {
        const int col = nt * 16 + ln;
        const float bv = b2[col];
        f4 acc = {bv, bv, bv, bv};
#pragma unroll
        for (int ks = 0; ks < HID_C / 32; ++ks) {
            const h8 af = *(const h8*)&s_t[w][ln][ks * 32 + quad * 8];
            const h8 bf = *(const h8*)(w2t + (size_t)col * HID_C + ks * 32 + quad * 8);
            acc = __builtin_amdgcn_mfma_f32_16x16x32_f16(af, bf, acc, 0, 0, 0);
        }
#pragma unroll
        for (int r = 0; r < 4; ++r) {
            const int node = node0 + quad * 4 + r;
            const float v = fmaxf(acc[r], 0.f);
            if (LASTL) {
                hout[(size_t)node * HID_C + col] = v;
            } else {
                h16out[(size_t)node * HID_C + col] = (_Float16)v;
            }
        }
    }
}

// ---------------------------------------------------------------------------
// Pool + output MLP (unchanged).
// ---------------------------------------------------------------------------
__global__ __launch_bounds__(256) void pool_kernel(
    const float* __restrict__ hfin, const int* __restrict__ batch,
    const float* __restrict__ w1, const float* __restrict__ b1,
    const float* __restrict__ w2, const float* __restrict__ b2,
    float* __restrict__ out, int n_nodes)
{
    const int gid = blockIdx.x;

    int lo = 0, hi = n_nodes;
    while (lo < hi) { int mid = (lo + hi) >> 1; if (batch[mid] < gid) lo = mid + 1; else hi = mid; }
    const int start = lo;
    hi = n_nodes;
    while (lo < hi) { int mid = (lo + hi) >> 1; if (batch[mid] < gid + 1) lo = mid + 1; else hi = mid; }
    const int end = lo;

    const int f = threadIdx.x & (HID_C - 1);
    const int half = threadIdx.x >> 7;

    float sum = 0.f;
    for (int n = start + half; n < end; n += 2)
        sum += hfin[(size_t)n * HID_C + f];

    __shared__ float s_sum[2][HID_C];
    __shared__ float s_p[HID_C];
    __shared__ float s_t[HID_C];
    s_sum[half][f] = sum;
    __syncthreads();

    if (threadIdx.x < HID_C) {
        const float cnt = (float)(end - start);
        s_p[f] = (s_sum[0][f] + s_sum[1][f]) / fmaxf(cnt, 1.f);
    }
    __syncthreads();

    if (threadIdx.x < HID_C) {
        float acc = b1[f];
        for (int k = 0; k < HID_C; ++k) acc = fmaf(s_p[k], w1[k * HID_C + f], acc);
        s_t[f] = fmaxf(acc, 0.f);
    }
    __syncthreads();

    if (threadIdx.x < HID_C) {
        float acc = b2[f];
        for (int k = 0; k < HID_C; ++k) acc = fmaf(s_t[k], w2[k * HID_C + f], acc);
        out[(size_t)gid * HID_C + f] = acc;
    }
}

// ---------------------------------------------------------------------------
extern "C" void kernel_launch(void* const* d_in, const int* in_sizes, int n_in,
                              void* d_out, int out_size, void* d_ws, size_t ws_size,
                              hipStream_t stream)
{
    const float* x         = (const float*)d_in[0];
    const float* edge_attr = (const float*)d_in[1];
    const int*   edge_index= (const int*)  d_in[2];
    const int*   batch     = (const int*)  d_in[3];
    const int*   src = edge_index;
    const int*   dst = edge_index + N_EDGES_C;

    const float* el_w[3] = {(const float*)d_in[4],  (const float*)d_in[12], (const float*)d_in[20]};
    const float* el_b[3] = {(const float*)d_in[5],  (const float*)d_in[13], (const float*)d_in[21]};
    const float* c_w1[3] = {(const float*)d_in[6],  (const float*)d_in[14], (const float*)d_in[22]};
    const float* c_b1[3] = {(const float*)d_in[7],  (const float*)d_in[15], (const float*)d_in[23]};
    const float* c_g [3] = {(const float*)d_in[8],  (const float*)d_in[16], (const float*)d_in[24]};
    const float* c_bt[3] = {(const float*)d_in[9],  (const float*)d_in[17], (const float*)d_in[25]};
    const float* c_w2[3] = {(const float*)d_in[10], (const float*)d_in[18], (const float*)d_in[26]};
    const float* c_b2[3] = {(const float*)d_in[11], (const float*)d_in[19], (const float*)d_in[27]};
    const float* o_w1 = (const float*)d_in[28];
    const float* o_b1 = (const float*)d_in[29];
    const float* o_w2 = (const float*)d_in[30];
    const float* o_b2 = (const float*)d_in[31];

    // ---- workspace layout ----
    char* wsp = (char*)d_ws;
    size_t used = 0;
    auto alloc = [&](size_t bytes) { char* p = wsp + used; used += (bytes + 255) & ~(size_t)255; return p; };
    float* h        = (float*)alloc((size_t)N_NODES_C * HID_C * 4);   // final f32 (pool input)
    int*   counts   = (int*)alloc((size_t)N_NODES_C * 4);
    int*   incl     = (int*)alloc((size_t)N_NODES_C * 4);
    int*   rowstart = (int*)alloc((size_t)N_NODES_C * 4);
    int*   cursor   = (int*)alloc((size_t)N_NODES_C * 4);
    int*   blocksums= (int*)alloc(128 * 4);
    int*   blockoffs= (int*)alloc(128 * 4);
    int*   perm_src = (int*)alloc((size_t)N_EDGES_C * 4);
    int*   perm_eid = (int*)alloc((size_t)N_EDGES_C * 4);
    _Float16* ea_f16 = (_Float16*)alloc((size_t)N_EDGES_C * 16 * 2);
    _Float16* h16_a  = (_Float16*)alloc((size_t)N_NODES_C * HID_C * 2);
    _Float16* h16_b  = (_Float16*)alloc((size_t)N_NODES_C * HID_C * 2);
    _Float16* x_f16  = (_Float16*)alloc((size_t)N_NODES_C * 64 * 2);
    _Float16* w1t[3], *w2t[3];
    for (int l = 0; l < 3; ++l) {
        w1t[l] = (_Float16*)alloc((size_t)HID_C * HID_C * 2);
        w2t[l] = (_Float16*)alloc((size_t)HID_C * HID_C * 2);
    }
    (void)ws_size;

    // ---- CSR build (once; reused by all 3 layers) ----
    hipMemsetAsync(counts, 0, (size_t)N_NODES_C * 4, stream);
    hist_kernel<<<(N_EDGES_C + 255) / 256, 256, 0, stream>>>(dst, counts, N_EDGES_C);
    scan1_kernel<<<SCAN_NB, SCAN_B, 0, stream>>>(counts, incl, blocksums, N_NODES_C);
    scan2_kernel<<<1, 64, 0, stream>>>(blocksums, blockoffs, SCAN_NB);
    scan3_kernel<<<SCAN_NB, SCAN_B, 0, stream>>>(incl, blockoffs, N_NODES_C);
    initrows_kernel<<<(N_NODES_C + 255) / 256, 256, 0, stream>>>(incl, counts, rowstart,
                                                                 cursor, N_NODES_C);
    scatter_kernel<<<(N_EDGES_C + 255) / 256, 256, 0, stream>>>(src, dst, cursor,
                                                                perm_src, perm_eid, N_EDGES_C);
    permute_ea_f16_kernel<<<(N_EDGES_C + 255) / 256, 256, 0, stream>>>(
        edge_attr, perm_eid, (__half*)ea_f16, N_EDGES_C);
    cast_f16_kernel<<<(N_NODES_C * 64 / 4 + 255) / 256, 256, 0, stream>>>(
        x, x_f16, N_NODES_C * 64 / 4);
    for (int l = 0; l < 3; ++l) {
        const int K1 = (l == 0) ? 64 : HID_C;
        transpose_w_kernel<<<(K1 * HID_C + 255) / 256, 256, 0, stream>>>(
            c_w1[l], w1t[l], K1, HID_C);
        transpose_w_kernel<<<(HID_C * HID_C + 255) / 256, 256, 0, stream>>>(
            c_w2[l], w2t[l], HID_C, HID_C);
    }

    const int n_tiles = N_NODES_C / 16;            // 6250
    const int nb = (n_tiles + 1) / 2;              // 3125 blocks x 128 threads

    // ---- 3 fused GINE layers ----
    gine_layer_kernel<64, false><<<nb, 128, 0, stream>>>(
        x_f16, ea_f16, perm_src, rowstart, incl,
        el_w[0], el_b[0], w1t[0], c_b1[0], c_g[0], c_bt[0], w2t[0], c_b2[0],
        h, h16_a, n_tiles);
    gine_layer_kernel<128, false><<<nb, 128, 0, stream>>>(
        h16_a, ea_f16, perm_src, rowstart, incl,
        el_w[1], el_b[1], w1t[1], c_b1[1], c_g[1], c_bt[1], w2t[1], c_b2[1],
        h, h16_b, n_tiles);
    gine_layer_kernel<128, true><<<nb, 128, 0, stream>>>(
        h16_b, ea_f16, perm_src, rowstart, incl,
        el_w[2], el_b[2], w1t[2], c_b1[2], c_g[2], c_bt[2], w2t[2], c_b2[2],
        h, h16_a, n_tiles);

    // ---- pool + output MLP ----
    pool_kernel<<<N_GRAPHS_C, 256, 0, stream>>>(h, batch, o_w1, o_b1, o_w2, o_b2,
                                                (float*)d_out, N_NODES_C);
}